// Round 1
// baseline (195.523 us; speedup 1.0000x reference)
//
#include <hip/hip_runtime.h>

// Problem constants (from reference setup_inputs)
constexpr int Bc = 8;
constexpr int Nc = 300;
constexpr int Cc = 256;
constexpr int Pc = 32;

// One block per query (b,n); 256 threads = one per channel.
__global__ __launch_bounds__(256) void sampling3d_kernel(
    const float* __restrict__ f0, const float* __restrict__ f1,
    const float* __restrict__ f2, const float* __restrict__ f3,
    const float* __restrict__ qpos, const float* __restrict__ qcont,
    const float* __restrict__ Woff, const float* __restrict__ boff,
    const float* __restrict__ sigma, float* __restrict__ out)
{
    const int q = blockIdx.x;        // b*N + n
    const int b = q / Nc;
    const int c = threadIdx.x;       // channel

    // ---- offsets = qcont[q,:] @ Woff + boff  (block reduction over C) ----
    float qc = qcont[q * Cc + c];
    float p0 = qc * Woff[c * 3 + 0];
    float p1 = qc * Woff[c * 3 + 1];
    float p2 = qc * Woff[c * 3 + 2];
#pragma unroll
    for (int off = 32; off > 0; off >>= 1) {
        p0 += __shfl_down(p0, off, 64);
        p1 += __shfl_down(p1, off, 64);
        p2 += __shfl_down(p2, off, 64);
    }
    __shared__ float red[4][3];
    __shared__ float par[8];   // sx, sy, zw[0..3]
    const int wave = threadIdx.x >> 6;
    const int lane = threadIdx.x & 63;
    if (lane == 0) { red[wave][0] = p0; red[wave][1] = p1; red[wave][2] = p2; }
    __syncthreads();
    if (threadIdx.x == 0) {
        float dx = red[0][0] + red[1][0] + red[2][0] + red[3][0] + boff[0];
        float dy = red[0][1] + red[1][1] + red[2][1] + red[3][1] + boff[1];
        float dz = red[0][2] + red[1][2] + red[2][2] + red[3][2] + boff[2];
        float x = qpos[q * 4 + 0];
        float y = qpos[q * 4 + 1];
        float z = qpos[q * 4 + 2];
        float r = qpos[q * 4 + 3];
        float sx = x + dx * exp2f(z - r);
        float sy = y + dy * exp2f(z + r);
        float sz = z + dz;
        float sg = sigma[0];
        float inv = 1.0f / (2.0f * sg * sg);
        // gaussian weights, then softmax OF those weights (as in source)
        float e[4];
        float s = 0.f;
#pragma unroll
        for (int l = 0; l < 4; ++l) {
            float d = sz - (float)l;
            float w = expf(-d * d * inv);   // in (0,1]
            e[l] = expf(w);                 // softmax numerator (no max-sub needed)
            s += e[l];
        }
        float rs = 1.0f / s;
        par[0] = sx;
        par[1] = sy;
#pragma unroll
        for (int l = 0; l < 4; ++l) par[2 + l] = e[l] * rs;
    }
    __syncthreads();

    const float sx = par[0];
    const float sy = par[1];

    const float* const fs[4] = {f0, f1, f2, f3};
    const int HWs[4] = {100, 50, 25, 13};   // square levels

    float acc = 0.f;
#pragma unroll
    for (int l = 0; l < 4; ++l) {
        const int H = HWs[l];
        const int W = HWs[l];
        const float zw = par[2 + l];
        // bilinear, padding_mode='border', align_corners=False: px = clamp(sx-0.5, 0, W-1)
        float px = fminf(fmaxf(sx - 0.5f, 0.f), (float)(W - 1));
        float py = fminf(fmaxf(sy - 0.5f, 0.f), (float)(H - 1));
        float x0f = floorf(px);
        float y0f = floorf(py);
        float wx = px - x0f;
        float wy = py - y0f;
        int x0 = (int)x0f;
        int y0 = (int)y0f;
        int x1 = min(x0 + 1, W - 1);
        int y1 = min(y0 + 1, H - 1);
        const float* base = fs[l] + (size_t)((b * Cc + c) * H) * W;
        float v00 = base[y0 * W + x0];
        float v01 = base[y0 * W + x1];
        float v10 = base[y1 * W + x0];
        float v11 = base[y1 * W + x1];
        float top = v00 + wx * (v01 - v00);
        float bot = v10 + wx * (v11 - v10);
        acc += zw * (top + wy * (bot - top));
    }

    // broadcast over P_IN: out[b,n,p,c] = acc for all p
    float* o = out + (size_t)q * (Pc * Cc) + c;
#pragma unroll
    for (int p = 0; p < Pc; ++p) o[p * Cc] = acc;
}

extern "C" void kernel_launch(void* const* d_in, const int* in_sizes, int n_in,
                              void* d_out, int out_size, void* d_ws, size_t ws_size,
                              hipStream_t stream) {
    const float* f0    = (const float*)d_in[0];
    const float* f1    = (const float*)d_in[1];
    const float* f2    = (const float*)d_in[2];
    const float* f3    = (const float*)d_in[3];
    const float* qpos  = (const float*)d_in[4];
    const float* qcont = (const float*)d_in[5];
    const float* Woff  = (const float*)d_in[6];
    const float* boff  = (const float*)d_in[7];
    const float* sigma = (const float*)d_in[8];
    float* out = (float*)d_out;

    sampling3d_kernel<<<Bc * Nc, 256, 0, stream>>>(
        f0, f1, f2, f3, qpos, qcont, Woff, boff, sigma, out);
}